// Round 10
// baseline (89.781 us; speedup 1.0000x reference)
//
#include <hip/hip_runtime.h>

#define L_SIG 3000
#define KPAD 3008           // 47*64
#define NB 8
#define CIN 64
#define COUT 128
#define KW 25
#define TOUT 2976
#define FMAXB 973
#define NCOLS 1946          // 2*FMAXB
#define NPAD 2048           // 16*128 (B rows, padded)
#define TSTRIDE 2000        // T cols (halfs)
#define TROWS 3072          // 24*128 (T rows, padded)
#define PSTRIDE (NPAD * 512)   // f32 per Sp part

// ws byte layout (~70 MB of ~268 MB; NO aliasing):
//  [0,        3080192)   A_fwd f16 [512][3008], pre-swizzled
//  [3145728, 15466496)   B_fwd f16 [2048][3008], pre-swizzled (rows>=1946 zero)
//  [15728640,28016640)   T_idft f16 [3072][2000], linear
//  [28311552,34936832)   Wc f16 (3,312,640 halfs)
//  [35651584,69206016)   S_part f32 [8][2048][512]
//  [69206016,70254592)   A_idft f16 (524,288 halfs)
#define A_BYTE    0
#define B_BYTE    3145728
#define T_BYTE    15728640
#define WC_BYTE   28311552
#define SP_BYTE   35651584
#define AID_BYTE  69206016

typedef _Float16 f16x8 __attribute__((ext_vector_type(8)));
typedef float f32x4 __attribute__((ext_vector_type(4)));

typedef __attribute__((address_space(1))) const unsigned GU;
typedef __attribute__((address_space(3))) unsigned LU;
#define GL16(g, l) __builtin_amdgcn_global_load_lds((GU*)(g), (LU*)(l), 16, 0, 0)

#define TWO_PI_OVER_L 0.00209439510239319549f

__device__ __forceinline__ float2 h2f2(unsigned u) {
    union { unsigned u; _Float16 h[2]; } p; p.u = u;
    return make_float2((float)p.h[0], (float)p.h[1]);
}
__device__ __forceinline__ unsigned f2h2(float a, float b) {
    union { unsigned u; _Float16 h[2]; } p;
    p.h[0] = (_Float16)a; p.h[1] = (_Float16)b; return p.u;
}

// ================= fused prep (r7 form, extended pad ranges) ============
// blocks: [0,1024) gen_a  [1024,5120) gen_b  [5120,8192) gen_t
//         [8192,8448) w_dft  [8448,8704) zero Aid
__global__ __launch_bounds__(256) void k_prep(const float* __restrict__ sig,
                                              const float* __restrict__ w,
                                              char* __restrict__ wsb) {
    __shared__ float wL[CIN * KW];
    int blk = blockIdx.x, tid = threadIdx.x;

    if (blk < 1024) {                        // ---- gen A_fwd (swizzled)
        _Float16* A = (_Float16*)(wsb + A_BYTE);
        int row = blk >> 1;
        int g = (blk & 1) * 256 + tid;
        if (g >= KPAD / 8) return;
        int gsw = (g & ~7) | ((g & 7) ^ (row & 7));
        union { _Float16 h[8]; uint4 u; } p;
        if (g < L_SIG / 8) {
            const float4* s4 = (const float4*)(sig + (size_t)row * L_SIG + g * 8);
            float4 a = s4[0], b = s4[1];
            p.h[0]=(_Float16)a.x; p.h[1]=(_Float16)a.y; p.h[2]=(_Float16)a.z; p.h[3]=(_Float16)a.w;
            p.h[4]=(_Float16)b.x; p.h[5]=(_Float16)b.y; p.h[6]=(_Float16)b.z; p.h[7]=(_Float16)b.w;
        } else p.u = make_uint4(0, 0, 0, 0);
        ((uint4*)A)[(size_t)row * (KPAD / 8) + gsw] = p.u;

    } else if (blk < 5120) {                 // ---- gen B_fwd (swizzled)
        _Float16* B = (_Float16*)(wsb + B_BYTE);
        int q = blk - 1024;
        int n = q >> 1;                      // 0..2047
        int g = (q & 1) * 256 + tid;
        if (g >= KPAD / 8) return;
        int f = n >> 1, c = n & 1;
        int gsw = (g & ~7) | ((g & 7) ^ (n & 7));
        union { _Float16 h[8]; uint4 u; } p;
        p.u = make_uint4(0, 0, 0, 0);
        if (f < FMAXB && g < L_SIG / 8) {
            int k0 = g * 8;
            int m0 = (int)(((long long)f * k0) % 3000);
            float s0, c0, sw, cw;
            __sincosf((float)m0 * TWO_PI_OVER_L, &s0, &c0);
            __sincosf((float)f * TWO_PI_OVER_L, &sw, &cw);
            float rr = c0, ri = -s0;         // e^{-i 2pi f k0/L}
            #pragma unroll
            for (int j = 0; j < 8; ++j) {
                p.h[j] = (_Float16)(c ? ri : rr);
                float nr = rr * cw + ri * sw;
                float ni = ri * cw - rr * sw;
                rr = nr; ri = ni;
            }
        }
        ((uint4*)B)[(size_t)n * (KPAD / 8) + gsw] = p.u;

    } else if (blk < 8192) {                 // ---- gen T_idft (linear)
        _Float16* T = (_Float16*)(wsb + T_BYTE);
        int t = blk - 5120;                  // 0..3071
        int g = tid;
        if (g >= TSTRIDE / 8) return;
        union { _Float16 h[8]; uint4 u; } p;
        p.u = make_uint4(0, 0, 0, 0);
        int f0 = g * 4;
        if (f0 < FMAXB) {
            int m0 = (int)(((long long)f0 * t) % 3000);
            float s0, c0, sw, cw;
            __sincosf((float)m0 * TWO_PI_OVER_L, &s0, &c0);
            __sincosf((float)t * TWO_PI_OVER_L, &sw, &cw);
            float rr = c0, ri = -s0;         // (cos,-sin) at f0
            #pragma unroll
            for (int j = 0; j < 4; ++j) {
                if (f0 + j < FMAXB) {
                    p.h[2 * j]     = (_Float16)rr;
                    p.h[2 * j + 1] = (_Float16)ri;
                }
                float nr = rr * cw + ri * sw;
                float ni = ri * cw - rr * sw;
                rr = nr; ri = ni;
            }
        }
        ((uint4*)T)[(size_t)t * (TSTRIDE / 8) + g] = p.u;

    } else if (blk < 8448) {                 // ---- weight DFT (conj)
        _Float16* Wc = (_Float16*)(wsb + WC_BYTE);
        const int startv[5] = {0,122,244,366,488};
        const int binsv[5]  = {123,123,123,123,485};
        const int n_ov[5]   = {25,25,25,25,28};
        const size_t wbase[5] = {0, 393600, 787200, 1180800, 1574400};  // halfs
        int q = blk - 8192;
        int o = q >> 1;
        int f = (q & 1) * 256 + tid;
        int band = min(o / 25, 4);
        int o_local = o - band * 25;
        int bins = binsv[band];
        const float* wrow = w + (size_t)o * CIN * KW;
        for (int k = tid; k < CIN * KW; k += 256) wL[k] = wrow[k];
        __syncthreads();
        if (f >= bins) return;
        int n_o = n_ov[band];
        int fg = startv[band] + f;
        float ws_, wc_;
        __sincosf((float)fg * TWO_PI_OVER_L, &ws_, &wc_);
        float wr = wc_, wi = ws_;            // conj roots: +sin
        unsigned* outp = (unsigned*)Wc + (wbase[band] >> 1) + ((size_t)f * n_o + o_local) * 64;
        for (int i = 0; i < CIN; ++i) {
            float ar = 0.f, ai = 0.f;
            float rr = 1.0f, ri = 0.0f;
            const float* wv = wL + i * KW;
            #pragma unroll
            for (int t = 0; t < KW; ++t) {
                float x = wv[t];
                ar = fmaf(x, rr, ar);
                ai = fmaf(x, ri, ai);
                float nr = fmaf(-ri, wi, rr * wr);
                float ni = fmaf( ri, wr, rr * wi);
                rr = nr; ri = ni;
            }
            outp[i] = f2h2(ar, ai);
        }

    } else {                                 // ---- zero A_idft
        uint4* Az = (uint4*)(wsb + AID_BYTE);
        int q = blk - 8448;
        Az[(size_t)q * 256 + tid] = make_uint4(0, 0, 0, 0);   // 65536 uint4
    }
}

// ==== fwd MFMA GEMM: 128x128 tile, 64x64/wave, split-K x8, drain loop ===
// grid (16, 32): y&3 = Mtile, y>>2 = kh. Output f32 [kh][col 2048][row 512].
__global__ __launch_bounds__(256) void k_dft_mm(const _Float16* __restrict__ A,
                                                const _Float16* __restrict__ B,
                                                float* __restrict__ Sp) {
    __shared__ _Float16 As[2][128 * 64];     // 32 KB
    __shared__ _Float16 Bs[2][128 * 64];     // 32 KB
    int row0 = (blockIdx.y & 3) * 128;
    int kh   = blockIdx.y >> 2;              // 0..7
    int col0 = blockIdx.x * 128;
    int kt0  = kh * 6;
    int nkt  = (kh == 7) ? 5 : 6;            // 47 = 7*6 + 5
    int tid = threadIdx.x, wid = tid >> 6, lane = tid & 63;
    int wr = wid >> 1, wc = wid & 1;
    f32x4 acc[4][4] = {};

    auto stage = [&](int kt, int buf) {      // 8 GL16 per thread
        int k0 = (kt0 + kt) * 64;
        #pragma unroll
        for (int it = 0; it < 4; ++it) {
            int cb = it * 256 + wid * 64;
            int cA = cb + lane;
            int ar = cA >> 3, cir = cA & 7;
            GL16((const char*)A + ((size_t)(row0 + ar) * KPAD + k0) * 2 + cir * 16,
                 (char*)As[buf] + cb * 16);
            GL16((const char*)B + ((size_t)(col0 + ar) * KPAD + k0) * 2 + cir * 16,
                 (char*)Bs[buf] + cb * 16);
        }
    };
    stage(0, 0);
    for (int kt = 0; kt < nkt; ++kt) {
        int cur = kt & 1;
        asm volatile("s_waitcnt vmcnt(0)" ::: "memory");
        __syncthreads();
        if (kt + 1 < nkt) stage(kt + 1, cur ^ 1);
        #pragma unroll
        for (int ks = 0; ks < 2; ++ks) {
            f16x8 av[4], bv[4];
            #pragma unroll
            for (int m = 0; m < 4; ++m) {
                int r = wr * 64 + m * 16 + (lane & 15);
                int g = (ks * 4 + (lane >> 4)) ^ (r & 7);
                av[m] = *(const f16x8*)(As[cur] + r * 64 + g * 8);
            }
            #pragma unroll
            for (int n = 0; n < 4; ++n) {
                int r = wc * 64 + n * 16 + (lane & 15);
                int g = (ks * 4 + (lane >> 4)) ^ (r & 7);
                bv[n] = *(const f16x8*)(Bs[cur] + r * 64 + g * 8);
            }
            #pragma unroll
            for (int m = 0; m < 4; ++m)
                #pragma unroll
                for (int n = 0; n < 4; ++n)
                    acc[m][n] = __builtin_amdgcn_mfma_f32_16x16x32_f16(
                        av[m], bv[n], acc[m][n], 0, 0, 0);
        }
    }
    float* outp = Sp + (size_t)kh * PSTRIDE;
    #pragma unroll
    for (int m = 0; m < 4; ++m)
        #pragma unroll
        for (int n = 0; n < 4; ++n) {
            int col = col0 + wc * 64 + n * 16 + (lane & 15);
            int rowb = row0 + wr * 64 + m * 16 + (lane >> 4) * 4;
            *(float4*)(outp + (size_t)col * 512 + rowb) = *(float4*)&acc[m][n];
        }
}

// ================ mix: one block per (band, f_local) bin ================
__global__ __launch_bounds__(256) void k_mix(const float* __restrict__ Sp,
                                             const _Float16* __restrict__ Wc,
                                             _Float16* __restrict__ Aid) {
    __shared__ float s_re[8 * 72];           // [b][i], pitch 72
    __shared__ float s_im[8 * 72];
    const int startv[5] = {0,122,244,366,488};
    const int n_ov[5]   = {25,25,25,25,28};
    const int dltv[5]   = {0,4,0,4,0};
    const int khv[5]    = {256,256,256,256,1024};
    const size_t wbase[5] = {0, 393600, 787200, 1180800, 1574400};  // halfs
    const size_t abase[5] = {0, 65536, 131072, 196608, 262144};     // halfs
    const int cumb[6] = {0, 123, 246, 369, 492, 977};
    int blk = blockIdx.x, tid = threadIdx.x;
    int band = 0;
    while (blk >= cumb[band + 1]) band++;
    int f_local = blk - cumb[band];
    int fg = startv[band] + f_local;

    const float* p0 = Sp + (size_t)(2 * fg) * 512;      // re col, part0
    #pragma unroll
    for (int e = 0; e < 2; ++e) {
        int row = tid + e * 256;                         // b*64+i
        int b = row >> 6, i = row & 63;
        float re = 0.f, im = 0.f;
        #pragma unroll
        for (int q = 0; q < 8; ++q) {
            re += p0[row + (size_t)q * PSTRIDE];
            im += p0[512 + row + (size_t)q * PSTRIDE];
        }
        s_re[b * 72 + i] = re;
        s_im[b * 72 + i] = im;
    }
    __syncthreads();

    int o_local = tid >> 3, b = tid & 7;
    int n_o = n_ov[band];
    if (o_local >= n_o) return;
    const uint4* wp4 = (const uint4*)((const unsigned*)Wc + (wbase[band] >> 1) +
                                      ((size_t)f_local * n_o + o_local) * 64);
    const float* lre = s_re + b * 72;
    const float* lim = s_im + b * 72;
    float xr = 0.f, xi = 0.f;
    #pragma unroll
    for (int ii = 0; ii < 16; ++ii) {
        float4 r4 = *(const float4*)(lre + ii * 4);
        float4 i4 = *(const float4*)(lim + ii * 4);
        uint4 wq = wp4[ii];
        float2 wv;
        wv = h2f2(wq.x);
        xr = fmaf(r4.x, wv.x, xr); xr = fmaf(-i4.x, wv.y, xr);
        xi = fmaf(r4.x, wv.y, xi); xi = fmaf( i4.x, wv.x, xi);
        wv = h2f2(wq.y);
        xr = fmaf(r4.y, wv.x, xr); xr = fmaf(-i4.y, wv.y, xr);
        xi = fmaf(r4.y, wv.y, xi); xi = fmaf( i4.y, wv.x, xi);
        wv = h2f2(wq.z);
        xr = fmaf(r4.z, wv.x, xr); xr = fmaf(-i4.z, wv.y, xr);
        xi = fmaf(r4.z, wv.y, xi); xi = fmaf( i4.z, wv.x, xi);
        wv = h2f2(wq.w);
        xr = fmaf(r4.w, wv.x, xr); xr = fmaf(-i4.w, wv.y, xr);
        xi = fmaf(r4.w, wv.y, xi); xi = fmaf( i4.w, wv.x, xi);
    }
    float scale = (fg == 0 ? 1.0f : 2.0f) / 3000.0f;
    size_t hoff = abase[band] + (size_t)(o_local * 8 + b) * khv[band] + 2 * f_local + dltv[band];
    ((unsigned*)Aid)[hoff >> 1] = f2h2(xr * scale, xi * scale);
}

// ===== idft MFMA GEMM: 128x128 tile, 64x64/wave, drain loop, + bias =====
// grid (24, 10): y>>1 = band, y&1 = Mtile.
__global__ __launch_bounds__(256) void k_idft_mm(const _Float16* __restrict__ Aid,
                                                 const _Float16* __restrict__ T,
                                                 const float* __restrict__ bias,
                                                 float* __restrict__ out) {
    __shared__ _Float16 As[2][128 * 64];
    __shared__ _Float16 Bs[2][128 * 64];
    const int n0v[5] = {0, 240, 488, 728, 976};
    const int n_ov[5] = {25,25,25,25,28};
    const size_t abase[5] = {0, 65536, 131072, 196608, 262144};
    int mt = blockIdx.y;                 // 0..9
    int band = mt >> 1;
    int row0b = (mt & 1) * 128;
    int col0 = blockIdx.x * 128;         // t tile (0..3071)
    int Kh = (band < 4) ? 256 : 1024;
    int nkt = Kh / 64;
    const char* Ab = (const char*)Aid + abase[band] * 2;
    const char* Bb = (const char*)T + (size_t)n0v[band] * 2;
    int tid = threadIdx.x, wid = tid >> 6, lane = tid & 63;
    int wr = wid >> 1, wc = wid & 1;
    f32x4 acc[4][4] = {};

    auto stage = [&](int kt, int buf) {
        int k0 = kt * 64;
        #pragma unroll
        for (int it = 0; it < 4; ++it) {
            int cb = it * 256 + wid * 64;
            int cA = cb + lane;
            int ar = cA >> 3, cir = cA & 7;
            int cirs = cir ^ (ar & 7);       // swizzle in SOURCE addr
            GL16(Ab + ((size_t)(row0b + ar) * Kh + k0) * 2 + cirs * 16,
                 (char*)As[buf] + cb * 16);
            GL16(Bb + ((size_t)(col0 + ar) * TSTRIDE + k0) * 2 + cirs * 16,
                 (char*)Bs[buf] + cb * 16);
        }
    };
    stage(0, 0);
    for (int kt = 0; kt < nkt; ++kt) {
        int cur = kt & 1;
        asm volatile("s_waitcnt vmcnt(0)" ::: "memory");
        __syncthreads();
        if (kt + 1 < nkt) stage(kt + 1, cur ^ 1);
        #pragma unroll
        for (int ks = 0; ks < 2; ++ks) {
            f16x8 av[4], bv[4];
            #pragma unroll
            for (int m = 0; m < 4; ++m) {
                int r = wr * 64 + m * 16 + (lane & 15);
                int g = (ks * 4 + (lane >> 4)) ^ (r & 7);
                av[m] = *(const f16x8*)(As[cur] + r * 64 + g * 8);
            }
            #pragma unroll
            for (int n = 0; n < 4; ++n) {
                int r = wc * 64 + n * 16 + (lane & 15);
                int g = (ks * 4 + (lane >> 4)) ^ (r & 7);
                bv[n] = *(const f16x8*)(Bs[cur] + r * 64 + g * 8);
            }
            #pragma unroll
            for (int m = 0; m < 4; ++m)
                #pragma unroll
                for (int n = 0; n < 4; ++n)
                    acc[m][n] = __builtin_amdgcn_mfma_f32_16x16x32_f16(
                        av[m], bv[n], acc[m][n], 0, 0, 0);
        }
    }
    int n_o8 = n_ov[band] * 8;
    #pragma unroll
    for (int m = 0; m < 4; ++m)
        #pragma unroll
        for (int n = 0; n < 4; ++n) {
            int t = col0 + wc * 64 + n * 16 + (lane & 15);
            if (t >= TOUT) continue;
            int rowb = row0b + wr * 64 + m * 16 + (lane >> 4) * 4;
            #pragma unroll
            for (int j = 0; j < 4; ++j) {
                int prb = rowb + j;
                if (prb < n_o8) {
                    int o = band * 25 + (prb >> 3);
                    int b = prb & 7;
                    out[((size_t)b * COUT + o) * TOUT + t] = acc[m][n][j] + bias[o];
                }
            }
        }
}

extern "C" void kernel_launch(void* const* d_in, const int* in_sizes, int n_in,
                              void* d_out, int out_size, void* d_ws, size_t ws_size,
                              hipStream_t stream) {
    const float* sig  = (const float*)d_in[0];   // (8,64,3000) f32
    const float* w    = (const float*)d_in[1];   // (128,64,25) f32
    const float* bias = (const float*)d_in[2];   // (128,) f32
    float* out = (float*)d_out;
    char* wsb = (char*)d_ws;
    _Float16* A   = (_Float16*)(wsb + A_BYTE);
    _Float16* B   = (_Float16*)(wsb + B_BYTE);
    _Float16* T   = (_Float16*)(wsb + T_BYTE);
    _Float16* Wc  = (_Float16*)(wsb + WC_BYTE);
    float*    Sp  = (float*)(wsb + SP_BYTE);
    _Float16* Aid = (_Float16*)(wsb + AID_BYTE);

    k_prep   <<<dim3(8704),   256, 0, stream>>>(sig, w, wsb);
    k_dft_mm <<<dim3(16, 32), 256, 0, stream>>>(A, B, Sp);
    k_mix    <<<dim3(977),    256, 0, stream>>>(Sp, Wc, Aid);
    k_idft_mm<<<dim3(24, 10), 256, 0, stream>>>(Aid, T, bias, out);
}

// Round 11
// 72.823 us; speedup vs baseline: 1.2329x; 1.2329x over previous
//
#include <hip/hip_runtime.h>

#define L_SIG 3000
#define KPAD2 1536          // folded K: 1504 -> 24*64
#define NB 8
#define CIN 64
#define COUT 128
#define KW 25
#define TOUT 2976
#define FMAXB 973
#define NFPAD 1024          // f columns padded (16*64)
#define TSTRIDE 2000        // T cols (halfs)
#define TROWS 3008          // 47*64
#define PSTRIDE2 (2048 * 512)  // f32 per Sp part (cols = 2*NFPAD)

// ws byte layout (~38 MB; NO aliasing):
//  [0,        1572864)   A_E f16 [512][1536]  xe, pre-swizzled
//  [1572864,  3145728)   A_O f16 [512][1536]  xo, pre-swizzled
//  [3145728,  6291456)   Bcos f16 [1024][1536], pre-swizzled
//  [6291456,  9437184)   Bsin f16 [1024][1536], pre-swizzled
//  [9437184, 21469184)   T_idft f16 [3008][2000], linear
//  [21469184,28094464)   Wc f16 (3,312,640 halfs)
//  [28311552,36700160)   S_part f32 [2][2048][512]
//  [36700160,37748736)   A_idft f16 (524,288 halfs)
#define AE_BYTE   0
#define AO_BYTE   1572864
#define BC_BYTE   3145728
#define BS_BYTE   6291456
#define T_BYTE    9437184
#define WC_BYTE   21469184
#define SP_BYTE   28311552
#define AID_BYTE  36700160

typedef _Float16 f16x8 __attribute__((ext_vector_type(8)));
typedef float f32x4 __attribute__((ext_vector_type(4)));

typedef __attribute__((address_space(1))) const unsigned GU;
typedef __attribute__((address_space(3))) unsigned LU;
#define GL16(g, l) __builtin_amdgcn_global_load_lds((GU*)(g), (LU*)(l), 16, 0, 0)

#define TWO_PI_OVER_L 0.00209439510239319549f

__device__ __forceinline__ float2 h2f2(unsigned u) {
    union { unsigned u; _Float16 h[2]; } p; p.u = u;
    return make_float2((float)p.h[0], (float)p.h[1]);
}
__device__ __forceinline__ unsigned f2h2(float a, float b) {
    union { unsigned u; _Float16 h[2]; } p;
    p.h[0] = (_Float16)a; p.h[1] = (_Float16)b; return p.u;
}

// ================= fused prep =========================================
// blocks: [0,512) fold xe/xo  [512,1536) Bcos  [1536,2560) Bsin
//         [2560,5568) gen_t  [5568,5824) w_dft  [5824,6080) zero Aid
__global__ __launch_bounds__(256) void k_prep(const float* __restrict__ sig,
                                              const float* __restrict__ w,
                                              char* __restrict__ wsb) {
    __shared__ float wL[CIN * KW];
    int blk = blockIdx.x, tid = threadIdx.x;

    if (blk < 512) {                         // ---- fold: xe / xo (swizzled)
        const float* x = sig + (size_t)blk * L_SIG;
        _Float16* AE = (_Float16*)(wsb + AE_BYTE);
        _Float16* AO = (_Float16*)(wsb + AO_BYTE);
        for (int g2 = tid; g2 < 384; g2 += 256) {
            int half = (g2 >= 192);
            int g = g2 - (half ? 192 : 0);
            union { _Float16 h[8]; uint4 u; } p;
            p.u = make_uint4(0, 0, 0, 0);
            if (g < 188) {
                int k0 = g * 8;
                float4 f0 = *(const float4*)(x + k0);
                float4 f1 = *(const float4*)(x + k0 + 4);
                float4 m0 = *(const float4*)(x + 2992 - k0);
                float4 m1 = *(const float4*)(x + 2996 - k0);
                float mir0 = k0 ? x[3000 - k0] : 0.f;
                float fwd[8]  = {f0.x,f0.y,f0.z,f0.w,f1.x,f1.y,f1.z,f1.w};
                float span[8] = {m0.x,m0.y,m0.z,m0.w,m1.x,m1.y,m1.z,m1.w};
                #pragma unroll
                for (int j = 0; j < 8; ++j) {
                    int k = k0 + j;
                    float mv = (j == 0) ? mir0 : span[8 - j];   // x[3000-k]
                    float xe, xo;
                    if (k == 0)         { xe = fwd[0];      xo = 0.f; }
                    else if (k < 1500)  { xe = fwd[j] + mv; xo = fwd[j] - mv; }
                    else if (k == 1500) { xe = fwd[j];      xo = 0.f; }
                    else                { xe = 0.f;         xo = 0.f; }
                    p.h[j] = (_Float16)(half ? xo : xe);
                }
            }
            int gsw = (g & ~7) | ((g & 7) ^ (blk & 7));
            ((uint4*)(half ? AO : AE))[(size_t)blk * 192 + gsw] = p.u;
        }

    } else if (blk < 2560) {                 // ---- Bcos / Bsin (swizzled)
        int isin = (blk >= 1536);
        int f = blk - (isin ? 1536 : 512);   // 0..1023
        _Float16* Bm = (_Float16*)(wsb + (isin ? BS_BYTE : BC_BYTE));
        int g = tid;
        if (g >= 192) return;
        union { _Float16 h[8]; uint4 u; } p;
        p.u = make_uint4(0, 0, 0, 0);
        if (f < FMAXB) {
            int k0 = g * 8;
            int m0 = (int)(((long long)f * k0) % 3000);
            float s0, c0, sw, cw;
            __sincosf((float)m0 * TWO_PI_OVER_L, &s0, &c0);
            __sincosf((float)f * TWO_PI_OVER_L, &sw, &cw);
            float rr = c0, ri = -s0;         // (cos, -sin) at k0
            #pragma unroll
            for (int j = 0; j < 8; ++j) {
                p.h[j] = (_Float16)(isin ? ri : rr);   // Bsin = -sin
                float nr = rr * cw + ri * sw;          // rotate by e^{-i 2pi f/L}
                float ni = ri * cw - rr * sw;
                rr = nr; ri = ni;
            }
        }
        int gsw = (g & ~7) | ((g & 7) ^ (f & 7));
        ((uint4*)Bm)[(size_t)f * 192 + gsw] = p.u;

    } else if (blk < 5568) {                 // ---- gen T_idft (linear)
        _Float16* T = (_Float16*)(wsb + T_BYTE);
        int t = blk - 2560;                  // 0..3007
        int g = tid;
        if (g >= TSTRIDE / 8) return;
        union { _Float16 h[8]; uint4 u; } p;
        p.u = make_uint4(0, 0, 0, 0);
        int f0 = g * 4;
        if (f0 < FMAXB) {
            int m0 = (int)(((long long)f0 * t) % 3000);
            float s0, c0, sw, cw;
            __sincosf((float)m0 * TWO_PI_OVER_L, &s0, &c0);
            __sincosf((float)t * TWO_PI_OVER_L, &sw, &cw);
            float rr = c0, ri = -s0;         // (cos,-sin) at f0
            #pragma unroll
            for (int j = 0; j < 4; ++j) {
                if (f0 + j < FMAXB) {
                    p.h[2 * j]     = (_Float16)rr;
                    p.h[2 * j + 1] = (_Float16)ri;
                }
                float nr = rr * cw + ri * sw;
                float ni = ri * cw - rr * sw;
                rr = nr; ri = ni;
            }
        }
        ((uint4*)T)[(size_t)t * (TSTRIDE / 8) + g] = p.u;

    } else if (blk < 5824) {                 // ---- weight DFT (conj)
        _Float16* Wc = (_Float16*)(wsb + WC_BYTE);
        const int startv[5] = {0,122,244,366,488};
        const int binsv[5]  = {123,123,123,123,485};
        const int n_ov[5]   = {25,25,25,25,28};
        const size_t wbase[5] = {0, 393600, 787200, 1180800, 1574400};  // halfs
        int q = blk - 5568;
        int o = q >> 1;
        int f = (q & 1) * 256 + tid;
        int band = min(o / 25, 4);
        int o_local = o - band * 25;
        int bins = binsv[band];
        const float* wrow = w + (size_t)o * CIN * KW;
        for (int k = tid; k < CIN * KW; k += 256) wL[k] = wrow[k];
        __syncthreads();
        if (f >= bins) return;
        int n_o = n_ov[band];
        int fg = startv[band] + f;
        float ws_, wc_;
        __sincosf((float)fg * TWO_PI_OVER_L, &ws_, &wc_);
        float wr = wc_, wi = ws_;            // conj roots: +sin
        unsigned* outp = (unsigned*)Wc + (wbase[band] >> 1) + ((size_t)f * n_o + o_local) * 64;
        for (int i = 0; i < CIN; ++i) {
            float ar = 0.f, ai = 0.f;
            float rr = 1.0f, ri = 0.0f;
            const float* wv = wL + i * KW;
            #pragma unroll
            for (int t = 0; t < KW; ++t) {
                float x = wv[t];
                ar = fmaf(x, rr, ar);
                ai = fmaf(x, ri, ai);
                float nr = fmaf(-ri, wi, rr * wr);
                float ni = fmaf( ri, wr, rr * wi);
                rr = nr; ri = ni;
            }
            outp[i] = f2h2(ar, ai);
        }

    } else {                                 // ---- zero A_idft
        uint4* Az = (uint4*)(wsb + AID_BYTE);
        int q = blk - 5824;
        Az[(size_t)q * 256 + tid] = make_uint4(0, 0, 0, 0);   // 65536 uint4
    }
}

// ==== folded fwd MFMA GEMM: 64x64 tile, splitK2, z = {re(cos,xe), im(sin,xo)}
// grid (16, 16, 2): x = f-tile, y&7 = Mtile, y>>3 = kh. Sp[kh][2f+z][row].
__global__ __launch_bounds__(256) void k_dft_mm(const char* __restrict__ wsb,
                                                float* __restrict__ Sp) {
    __shared__ _Float16 As[2][64 * 64];
    __shared__ _Float16 Bs[2][64 * 64];
    int z = blockIdx.z;
    const _Float16* A = (const _Float16*)(wsb + (z ? AO_BYTE : AE_BYTE));
    const _Float16* B = (const _Float16*)(wsb + (z ? BS_BYTE : BC_BYTE));
    int row0 = (blockIdx.y & 7) * 64;
    int kh   = blockIdx.y >> 3;
    int col0 = blockIdx.x * 64;
    int kt0  = kh * 12;
    const int nkt = 12;
    int tid = threadIdx.x, wid = tid >> 6, lane = tid & 63;
    int wr = wid >> 1, wc = wid & 1;
    f32x4 acc[2][2] = {};

    auto stage = [&](int kt, int buf) {      // 4 GL16 per thread
        int k0 = (kt0 + kt) * 64;
        #pragma unroll
        for (int it = 0; it < 2; ++it) {
            int cb = it * 256 + wid * 64;
            int cA = cb + lane;
            int ar = cA >> 3, cir = cA & 7;
            GL16((const char*)A + ((size_t)(row0 + ar) * KPAD2 + k0) * 2 + cir * 16,
                 (char*)As[buf] + cb * 16);
            GL16((const char*)B + ((size_t)(col0 + ar) * KPAD2 + k0) * 2 + cir * 16,
                 (char*)Bs[buf] + cb * 16);
        }
    };
    stage(0, 0);
    for (int kt = 0; kt < nkt; ++kt) {
        int cur = kt & 1;
        asm volatile("s_waitcnt vmcnt(0)" ::: "memory");
        __syncthreads();
        if (kt + 1 < nkt) stage(kt + 1, cur ^ 1);
        #pragma unroll
        for (int ks = 0; ks < 2; ++ks) {
            f16x8 av[2], bv[2];
            #pragma unroll
            for (int m = 0; m < 2; ++m) {
                int r = wr * 32 + m * 16 + (lane & 15);
                int g = (ks * 4 + (lane >> 4)) ^ (r & 7);
                av[m] = *(const f16x8*)(As[cur] + r * 64 + g * 8);
            }
            #pragma unroll
            for (int n = 0; n < 2; ++n) {
                int r = wc * 32 + n * 16 + (lane & 15);
                int g = (ks * 4 + (lane >> 4)) ^ (r & 7);
                bv[n] = *(const f16x8*)(Bs[cur] + r * 64 + g * 8);
            }
            #pragma unroll
            for (int m = 0; m < 2; ++m)
                #pragma unroll
                for (int n = 0; n < 2; ++n)
                    acc[m][n] = __builtin_amdgcn_mfma_f32_16x16x32_f16(
                        av[m], bv[n], acc[m][n], 0, 0, 0);
        }
    }
    float* outp = Sp + (size_t)kh * PSTRIDE2;
    #pragma unroll
    for (int m = 0; m < 2; ++m)
        #pragma unroll
        for (int n = 0; n < 2; ++n) {
            int colf = col0 + wc * 32 + n * 16 + (lane & 15);
            int scol = 2 * colf + z;
            int rowb = row0 + wr * 32 + m * 16 + (lane >> 4) * 4;
            *(float4*)(outp + (size_t)scol * 512 + rowb) = *(float4*)&acc[m][n];
        }
}

// ================ mix: one block per (band, f_local) bin ================
__global__ __launch_bounds__(256) void k_mix(const float* __restrict__ Sp,
                                             const _Float16* __restrict__ Wc,
                                             _Float16* __restrict__ Aid) {
    __shared__ float s_re[8 * 72];           // [b][i], pitch 72
    __shared__ float s_im[8 * 72];
    const int startv[5] = {0,122,244,366,488};
    const int n_ov[5]   = {25,25,25,25,28};
    const int dltv[5]   = {0,4,0,4,0};
    const int khv[5]    = {256,256,256,256,1024};
    const size_t wbase[5] = {0, 393600, 787200, 1180800, 1574400};  // halfs
    const size_t abase[5] = {0, 65536, 131072, 196608, 262144};     // halfs
    const int cumb[6] = {0, 123, 246, 369, 492, 977};
    int blk = blockIdx.x, tid = threadIdx.x;
    int band = 0;
    while (blk >= cumb[band + 1]) band++;
    int f_local = blk - cumb[band];
    int fg = startv[band] + f_local;

    const float* p0 = Sp + (size_t)(2 * fg) * 512;      // re col, part0
    const float* p1 = p0 + (size_t)PSTRIDE2;            // part1
    #pragma unroll
    for (int e = 0; e < 2; ++e) {
        int row = tid + e * 256;                         // b*64+i
        int b = row >> 6, i = row & 63;
        s_re[b * 72 + i] = p0[row] + p1[row];
        s_im[b * 72 + i] = p0[512 + row] + p1[512 + row];
    }
    __syncthreads();

    int o_local = tid >> 3, b = tid & 7;
    int n_o = n_ov[band];
    if (o_local >= n_o) return;
    const uint4* wp4 = (const uint4*)((const unsigned*)Wc + (wbase[band] >> 1) +
                                      ((size_t)f_local * n_o + o_local) * 64);
    const float* lre = s_re + b * 72;
    const float* lim = s_im + b * 72;
    float xr = 0.f, xi = 0.f;
    #pragma unroll
    for (int ii = 0; ii < 16; ++ii) {
        float4 r4 = *(const float4*)(lre + ii * 4);
        float4 i4 = *(const float4*)(lim + ii * 4);
        uint4 wq = wp4[ii];
        float2 wv;
        wv = h2f2(wq.x);
        xr = fmaf(r4.x, wv.x, xr); xr = fmaf(-i4.x, wv.y, xr);
        xi = fmaf(r4.x, wv.y, xi); xi = fmaf( i4.x, wv.x, xi);
        wv = h2f2(wq.y);
        xr = fmaf(r4.y, wv.x, xr); xr = fmaf(-i4.y, wv.y, xr);
        xi = fmaf(r4.y, wv.y, xi); xi = fmaf( i4.y, wv.x, xi);
        wv = h2f2(wq.z);
        xr = fmaf(r4.z, wv.x, xr); xr = fmaf(-i4.z, wv.y, xr);
        xi = fmaf(r4.z, wv.y, xi); xi = fmaf( i4.z, wv.x, xi);
        wv = h2f2(wq.w);
        xr = fmaf(r4.w, wv.x, xr); xr = fmaf(-i4.w, wv.y, xr);
        xi = fmaf(r4.w, wv.y, xi); xi = fmaf( i4.w, wv.x, xi);
    }
    float scale = (fg == 0 ? 1.0f : 2.0f) / 3000.0f;
    size_t hoff = abase[band] + (size_t)(o_local * 8 + b) * khv[band] + 2 * f_local + dltv[band];
    ((unsigned*)Aid)[hoff >> 1] = f2h2(xr * scale, xi * scale);
}

// ======== idft MFMA GEMM (r7-proven drain loop) + bias ==================
__global__ __launch_bounds__(256) void k_idft_mm(const _Float16* __restrict__ Aid,
                                                 const _Float16* __restrict__ T,
                                                 const float* __restrict__ bias,
                                                 float* __restrict__ out) {
    __shared__ _Float16 As[2][64 * 64];
    __shared__ _Float16 Bs[2][64 * 64];
    const int n0v[5] = {0, 240, 488, 728, 976};
    const int n_ov[5] = {25,25,25,25,28};
    const size_t abase[5] = {0, 65536, 131072, 196608, 262144};
    int mt = blockIdx.y;                 // 0..19
    int band = mt >> 2;
    int row0b = (mt & 3) * 64;
    int col0 = blockIdx.x * 64;
    int Kh = (band < 4) ? 256 : 1024;
    int nkt = Kh / 64;
    const char* Ab = (const char*)Aid + abase[band] * 2;
    const char* Bb = (const char*)T + (size_t)n0v[band] * 2;
    int tid = threadIdx.x, wid = tid >> 6, lane = tid & 63;
    int wr = wid >> 1, wc = wid & 1;
    f32x4 acc[2][2] = {};

    auto stage = [&](int kt, int buf) {
        int k0 = kt * 64;
        #pragma unroll
        for (int it = 0; it < 2; ++it) {
            int cb = it * 256 + wid * 64;
            int cA = cb + lane;
            int ar = cA >> 3, cir = cA & 7;
            int cirs = cir ^ (ar & 7);       // swizzle in SOURCE addr
            GL16(Ab + ((size_t)(row0b + ar) * Kh + k0) * 2 + cirs * 16,
                 (char*)As[buf] + cb * 16);
            GL16(Bb + ((size_t)(col0 + ar) * TSTRIDE + k0) * 2 + cirs * 16,
                 (char*)Bs[buf] + cb * 16);
        }
    };
    stage(0, 0);
    for (int kt = 0; kt < nkt; ++kt) {
        int cur = kt & 1;
        asm volatile("s_waitcnt vmcnt(0)" ::: "memory");
        __syncthreads();
        if (kt + 1 < nkt) stage(kt + 1, cur ^ 1);
        #pragma unroll
        for (int ks = 0; ks < 2; ++ks) {
            f16x8 av[2], bv[2];
            #pragma unroll
            for (int m = 0; m < 2; ++m) {
                int r = wr * 32 + m * 16 + (lane & 15);
                int g = (ks * 4 + (lane >> 4)) ^ (r & 7);
                av[m] = *(const f16x8*)(As[cur] + r * 64 + g * 8);
            }
            #pragma unroll
            for (int n = 0; n < 2; ++n) {
                int r = wc * 32 + n * 16 + (lane & 15);
                int g = (ks * 4 + (lane >> 4)) ^ (r & 7);
                bv[n] = *(const f16x8*)(Bs[cur] + r * 64 + g * 8);
            }
            #pragma unroll
            for (int m = 0; m < 2; ++m)
                #pragma unroll
                for (int n = 0; n < 2; ++n)
                    acc[m][n] = __builtin_amdgcn_mfma_f32_16x16x32_f16(
                        av[m], bv[n], acc[m][n], 0, 0, 0);
        }
    }
    int n_o8 = n_ov[band] * 8;
    #pragma unroll
    for (int m = 0; m < 2; ++m)
        #pragma unroll
        for (int n = 0; n < 2; ++n) {
            int t = col0 + wc * 32 + n * 16 + (lane & 15);
            if (t >= TOUT) continue;
            int rowb = row0b + wr * 32 + m * 16 + (lane >> 4) * 4;
            #pragma unroll
            for (int j = 0; j < 4; ++j) {
                int prb = rowb + j;
                if (prb < n_o8) {
                    int o = band * 25 + (prb >> 3);
                    int b = prb & 7;
                    out[((size_t)b * COUT + o) * TOUT + t] = acc[m][n][j] + bias[o];
                }
            }
        }
}

extern "C" void kernel_launch(void* const* d_in, const int* in_sizes, int n_in,
                              void* d_out, int out_size, void* d_ws, size_t ws_size,
                              hipStream_t stream) {
    const float* sig  = (const float*)d_in[0];   // (8,64,3000) f32
    const float* w    = (const float*)d_in[1];   // (128,64,25) f32
    const float* bias = (const float*)d_in[2];   // (128,) f32
    float* out = (float*)d_out;
    char* wsb = (char*)d_ws;
    _Float16* T   = (_Float16*)(wsb + T_BYTE);
    _Float16* Wc  = (_Float16*)(wsb + WC_BYTE);
    float*    Sp  = (float*)(wsb + SP_BYTE);
    _Float16* Aid = (_Float16*)(wsb + AID_BYTE);

    k_prep   <<<dim3(6080),       256, 0, stream>>>(sig, w, wsb);
    k_dft_mm <<<dim3(16, 16, 2),  256, 0, stream>>>(wsb, Sp);
    k_mix    <<<dim3(977),        256, 0, stream>>>(Sp, Wc, Aid);
    k_idft_mm<<<dim3(47, 20),     256, 0, stream>>>(Aid, T, bias, out);
}